// Round 4
// baseline (132.466 us; speedup 1.0000x reference)
//
#include <hip/hip_runtime.h>

// Round 3: barrier-free streaming attention (S^T trick => register-local P),
// pre-converted bf16 GEMM inputs, 128-wide MFMA GEMM tiles.
// Pipeline: cvt_bf16 -> qkv_mfma -> attn_stream -> out_mfma.
// ws (bytes): xb 4M | wqb 384K | wob 128K | Q 4M | K 4M | Vt 4M | Zb 4M ~ 20.5MB

#define SEQ 2048
#define BATCH 4
#define NHEADS 8
#define HDIM 32
#define DIMC 256
#define SCALE_LOG2E 0.09016844005556021f  // (1/16)*log2(e)

typedef __attribute__((ext_vector_type(8))) short short8;
typedef __attribute__((ext_vector_type(4))) float f32x4;

union BF8 { unsigned u[4]; short8 s8; };

__device__ __forceinline__ unsigned pk2bf(float a, float b) {
    union { float f; unsigned u; } ua, ub;
    ua.f = a; ub.f = b;
    return __builtin_amdgcn_perm(ub.u + 0x8000u, ua.u + 0x8000u, 0x07060302u);
}
__device__ __forceinline__ short f2bf(float a) {
    union { float f; unsigned u; } x; x.f = a;
    return (short)((x.u + 0x8000u) >> 16);
}

// ---------------------------------------------------------------------------
// Pre-convert x, w_qkv, w_out to bf16 (one pass, float4 -> packed bf16x4).
// ---------------------------------------------------------------------------
#define NX (BATCH * SEQ * DIMC)     // 2097152
#define NQW (3 * DIMC * DIMC)       // 196608
#define NOW (DIMC * DIMC)           // 65536

__global__ __launch_bounds__(256) void cvt_bf16(const float* __restrict__ x,
                                                const float* __restrict__ wq,
                                                const float* __restrict__ wo,
                                                short* __restrict__ xb,
                                                short* __restrict__ wqb,
                                                short* __restrict__ wob) {
    int i = (blockIdx.x * 256 + threadIdx.x) * 4;
    const float* src;
    short* dst;
    int off;
    if (i < NX) { src = x; dst = xb; off = i; }
    else if (i < NX + NQW) { src = wq; dst = wqb; off = i - NX; }
    else { src = wo; dst = wob; off = i - NX - NQW; }
    float4 v = *(const float4*)&src[off];
    uint2 p;
    p.x = pk2bf(v.x, v.y);
    p.y = pk2bf(v.z, v.w);
    *(uint2*)&dst[off] = p;
}

// ---------------------------------------------------------------------------
// QKV GEMM: C[8192][768] = Xb . Wb^T + b. 128x128 tile, 4 waves (2x2),
// BK=64, 32 MFMA/wave/iter. Epilogue: LDS-staged coalesced bf16 scatter:
// Q (pre-scaled by SCALE*log2e) / K -> [bh][tok][d]; V -> [bh][d][tok].
// ---------------------------------------------------------------------------
__global__ __launch_bounds__(256) void qkv_mfma(const short* __restrict__ Xb,
                                                const short* __restrict__ Wb,
                                                const float* __restrict__ bias,
                                                short* __restrict__ Q,
                                                short* __restrict__ Kd,
                                                short* __restrict__ V) {
    __shared__ __align__(16) union SM {
        struct { short A[128][72]; short B[128][72]; } ab;
        short C[128][136];
    } sm;
    const int m0 = blockIdx.y * 128, bx = blockIdx.x;
    const int tid = threadIdx.x;
    const int w = tid >> 6, lane = tid & 63;
    const int m = lane & 15, g = lane >> 4;
    const int wr = w >> 1, wc = w & 1;
    const int srow = tid >> 1, scol = (tid & 1) * 32;

    f32x4 acc[4][4] = {};

    for (int kt = 0; kt < DIMC; kt += 64) {
        short8 a8[4], b8[4];
#pragma unroll
        for (int i = 0; i < 4; i++) {
            a8[i] = *(const short8*)&Xb[(size_t)(m0 + srow) * DIMC + kt + scol + i * 8];
            b8[i] = *(const short8*)&Wb[(size_t)(bx * 128 + srow) * DIMC + kt + scol + i * 8];
        }
        __syncthreads();
#pragma unroll
        for (int i = 0; i < 4; i++) {
            *(short8*)&sm.ab.A[srow][scol + i * 8] = a8[i];
            *(short8*)&sm.ab.B[srow][scol + i * 8] = b8[i];
        }
        __syncthreads();
#pragma unroll
        for (int kk = 0; kk < 2; kk++) {
            short8 af[4], bf[4];
#pragma unroll
            for (int mt = 0; mt < 4; mt++) af[mt] = *(const short8*)&sm.ab.A[wr * 64 + mt * 16 + m][kk * 32 + g * 8];
#pragma unroll
            for (int nt = 0; nt < 4; nt++) bf[nt] = *(const short8*)&sm.ab.B[wc * 64 + nt * 16 + m][kk * 32 + g * 8];
#pragma unroll
            for (int mt = 0; mt < 4; mt++)
#pragma unroll
                for (int nt = 0; nt < 4; nt++)
                    acc[mt][nt] = __builtin_amdgcn_mfma_f32_16x16x32_bf16(af[mt], bf[nt], acc[mt][nt], 0, 0, 0);
        }
    }

    const int which = bx >> 1;            // 0=Q 1=K 2=V
    const int h0 = (bx & 1) * 4;          // first of 4 heads in this n-tile
    const int bidx = blockIdx.y >> 4;
    const int ntok0 = (blockIdx.y & 15) * 128;
    float bv[4];
#pragma unroll
    for (int nt = 0; nt < 4; nt++) bv[nt] = bias[bx * 128 + wc * 64 + nt * 16 + m];

    __syncthreads();
    if (which != 2) {
        const float qs = (which == 0) ? SCALE_LOG2E : 1.0f;
#pragma unroll
        for (int mt = 0; mt < 4; mt++)
#pragma unroll
            for (int nt = 0; nt < 4; nt++)
#pragma unroll
                for (int r = 0; r < 4; r++)
                    sm.C[wr * 64 + mt * 16 + g * 4 + r][wc * 64 + nt * 16 + m] =
                        f2bf((acc[mt][nt][r] + bv[nt]) * qs);
        __syncthreads();
        short* dst = (which == 0) ? Q : Kd;
        const int tok = tid >> 1, d0 = (tid & 1) * 16;
#pragma unroll
        for (int hh = 0; hh < 4; hh++) {
            size_t o = ((size_t)((bidx * NHEADS + h0 + hh) * SEQ) + ntok0 + tok) * HDIM + d0;
            *(short8*)&dst[o] = *(const short8*)&sm.C[tok][hh * 32 + d0];
            *(short8*)&dst[o + 8] = *(const short8*)&sm.C[tok][hh * 32 + d0 + 8];
        }
    } else {
        // stage transposed: C[d-col][token]
#pragma unroll
        for (int mt = 0; mt < 4; mt++)
#pragma unroll
            for (int nt = 0; nt < 4; nt++) {
                uint2 p;
                p.x = pk2bf(acc[mt][nt][0] + bv[nt], acc[mt][nt][1] + bv[nt]);
                p.y = pk2bf(acc[mt][nt][2] + bv[nt], acc[mt][nt][3] + bv[nt]);
                *(uint2*)&sm.C[wc * 64 + nt * 16 + m][wr * 64 + mt * 16 + g * 4] = p;
            }
        __syncthreads();
        const int col = tid >> 1, t0 = (tid & 1) * 64;
        const int hh = col >> 5, d = col & 31;
        size_t o = ((size_t)((bidx * NHEADS + h0 + hh) * HDIM) + d) * SEQ + ntok0 + t0;
#pragma unroll
        for (int c2 = 0; c2 < 8; c2++)
            *(short8*)&V[o + c2 * 8] = *(const short8*)&sm.C[col][t0 + c2 * 8];
    }
}

// ---------------------------------------------------------------------------
// Streaming flash attention: NO LDS, NO barriers. grid=(16 qtiles, 32 bh),
// 4 waves x 32 q-rows = 128 q-rows/block. KV tile 64/iter.
// S^T = K.Q^T with row-permuted K-frags (sigma) => P lands register-local in
// PV A-layout. l via ones-MFMA. Emits bf16 Z [tok][256].
// ---------------------------------------------------------------------------
__global__ __launch_bounds__(256) void attn_stream(const short* __restrict__ Q,
                                                   const short* __restrict__ K,
                                                   const short* __restrict__ V,  // [bh][d][tok]
                                                   short* __restrict__ Zb) {
    const int bh = blockIdx.y;
    const int b = bh >> 3, h = bh & 7;
    const int q0 = blockIdx.x * 128;
    const short* qb = Q + (size_t)bh * SEQ * HDIM;
    const short* kb = K + (size_t)bh * SEQ * HDIM;
    const short* vb = V + (size_t)bh * HDIM * SEQ;
    const int tid = threadIdx.x;
    const int w = tid >> 6, lane = tid & 63;
    const int m = lane & 15, g = lane >> 4;

    short8 qf[2];
    qf[0] = *(const short8*)(qb + (size_t)(q0 + w * 32 + m) * HDIM + g * 8);
    qf[1] = *(const short8*)(qb + (size_t)(q0 + w * 32 + 16 + m) * HDIM + g * 8);

    // sigma(t, i): K-row permutation so P exits S^T in PV A-layout per-lane.
    int koff[4];
#pragma unroll
    for (int t = 0; t < 4; t++) {
        int row = 32 * (t >> 1) + ((m >> 2) << 3) + ((t & 1) << 2) + (m & 3);
        koff[t] = row * HDIM + g * 8;
    }
    const int voff0 = m * SEQ + g * 8;
    const int voff1 = (m + 16) * SEQ + g * 8;

    f32x4 o00 = {0.f, 0.f, 0.f, 0.f}, o01 = {0.f, 0.f, 0.f, 0.f};
    f32x4 o10 = {0.f, 0.f, 0.f, 0.f}, o11 = {0.f, 0.f, 0.f, 0.f};
    f32x4 ol0 = {0.f, 0.f, 0.f, 0.f}, ol1 = {0.f, 0.f, 0.f, 0.f};
    const short8 ones = {0x3F80, 0x3F80, 0x3F80, 0x3F80, 0x3F80, 0x3F80, 0x3F80, 0x3F80};

    for (int k0 = 0; k0 < SEQ; k0 += 64) {
        short8 kf[4];
#pragma unroll
        for (int t = 0; t < 4; t++)
            kf[t] = *(const short8*)(kb + (size_t)k0 * HDIM + koff[t]);
        short8 vf00 = *(const short8*)(vb + voff0 + k0);
        short8 vf01 = *(const short8*)(vb + voff1 + k0);
        short8 vf10 = *(const short8*)(vb + voff0 + k0 + 32);
        short8 vf11 = *(const short8*)(vb + voff1 + k0 + 32);

#pragma unroll
        for (int qh = 0; qh < 2; qh++) {
            f32x4 st[4];
#pragma unroll
            for (int t = 0; t < 4; t++) {
                f32x4 z4 = {0.f, 0.f, 0.f, 0.f};
                st[t] = __builtin_amdgcn_mfma_f32_16x16x32_bf16(kf[t], qh ? qf[1] : qf[0], z4, 0, 0, 0);
            }
            BF8 a0, a1;
#pragma unroll
            for (int t = 0; t < 2; t++) {
                a0.u[t * 2 + 0] = pk2bf(__builtin_amdgcn_exp2f(st[t][0]), __builtin_amdgcn_exp2f(st[t][1]));
                a0.u[t * 2 + 1] = pk2bf(__builtin_amdgcn_exp2f(st[t][2]), __builtin_amdgcn_exp2f(st[t][3]));
                a1.u[t * 2 + 0] = pk2bf(__builtin_amdgcn_exp2f(st[t + 2][0]), __builtin_amdgcn_exp2f(st[t + 2][1]));
                a1.u[t * 2 + 1] = pk2bf(__builtin_amdgcn_exp2f(st[t + 2][2]), __builtin_amdgcn_exp2f(st[t + 2][3]));
            }
            if (qh == 0) {
                o00 = __builtin_amdgcn_mfma_f32_16x16x32_bf16(a0.s8, vf00, o00, 0, 0, 0);
                o01 = __builtin_amdgcn_mfma_f32_16x16x32_bf16(a0.s8, vf01, o01, 0, 0, 0);
                ol0 = __builtin_amdgcn_mfma_f32_16x16x32_bf16(a0.s8, ones, ol0, 0, 0, 0);
                o00 = __builtin_amdgcn_mfma_f32_16x16x32_bf16(a1.s8, vf10, o00, 0, 0, 0);
                o01 = __builtin_amdgcn_mfma_f32_16x16x32_bf16(a1.s8, vf11, o01, 0, 0, 0);
                ol0 = __builtin_amdgcn_mfma_f32_16x16x32_bf16(a1.s8, ones, ol0, 0, 0, 0);
            } else {
                o10 = __builtin_amdgcn_mfma_f32_16x16x32_bf16(a0.s8, vf00, o10, 0, 0, 0);
                o11 = __builtin_amdgcn_mfma_f32_16x16x32_bf16(a0.s8, vf01, o11, 0, 0, 0);
                ol1 = __builtin_amdgcn_mfma_f32_16x16x32_bf16(a0.s8, ones, ol1, 0, 0, 0);
                o10 = __builtin_amdgcn_mfma_f32_16x16x32_bf16(a1.s8, vf10, o10, 0, 0, 0);
                o11 = __builtin_amdgcn_mfma_f32_16x16x32_bf16(a1.s8, vf11, o11, 0, 0, 0);
                ol1 = __builtin_amdgcn_mfma_f32_16x16x32_bf16(a1.s8, ones, ol1, 0, 0, 0);
            }
        }
    }

#pragma unroll
    for (int qh = 0; qh < 2; qh++) {
        f32x4 oa = qh ? o10 : o00;
        f32x4 ob = qh ? o11 : o01;
        f32x4 ll = qh ? ol1 : ol0;
#pragma unroll
        for (int r = 0; r < 4; r++) {
            float inv = __builtin_amdgcn_rcpf(ll[r]);
            int row = q0 + w * 32 + qh * 16 + g * 4 + r;
            size_t zo = ((size_t)(b * SEQ + row)) * DIMC + h * HDIM + m;
            Zb[zo] = f2bf(oa[r] * inv);
            Zb[zo + 16] = f2bf(ob[r] * inv);
        }
    }
}

// ---------------------------------------------------------------------------
// Out GEMM: out[8192][256] = Zb . Wob^T + b (fp32 out). 128x64 tile, BK=64.
// ---------------------------------------------------------------------------
__global__ __launch_bounds__(256) void out_mfma(const short* __restrict__ A,
                                                const short* __restrict__ Wb,
                                                const float* __restrict__ bias,
                                                float* __restrict__ C) {
    __shared__ __align__(16) short As[128][72];
    __shared__ __align__(16) short Bs[64][72];
    const int m0 = blockIdx.y * 128, n0 = blockIdx.x * 64;
    const int tid = threadIdx.x;
    const int w = tid >> 6, lane = tid & 63;
    const int m = lane & 15, g = lane >> 4;
    const int wr = w >> 1, wc = w & 1;
    const int arow = tid >> 1, acol = (tid & 1) * 32;
    const int brow = tid >> 2, bcol = (tid & 3) * 16;

    f32x4 acc[4][2] = {};

    for (int kt = 0; kt < DIMC; kt += 64) {
        short8 a8[4], b8[2];
#pragma unroll
        for (int i = 0; i < 4; i++)
            a8[i] = *(const short8*)&A[(size_t)(m0 + arow) * DIMC + kt + acol + i * 8];
#pragma unroll
        for (int i = 0; i < 2; i++)
            b8[i] = *(const short8*)&Wb[(size_t)(n0 + brow) * DIMC + kt + bcol + i * 8];
        __syncthreads();
#pragma unroll
        for (int i = 0; i < 4; i++) *(short8*)&As[arow][acol + i * 8] = a8[i];
#pragma unroll
        for (int i = 0; i < 2; i++) *(short8*)&Bs[brow][bcol + i * 8] = b8[i];
        __syncthreads();
#pragma unroll
        for (int kk = 0; kk < 2; kk++) {
            short8 af[4], bf2[2];
#pragma unroll
            for (int mt = 0; mt < 4; mt++) af[mt] = *(const short8*)&As[wr * 64 + mt * 16 + m][kk * 32 + g * 8];
#pragma unroll
            for (int nt = 0; nt < 2; nt++) bf2[nt] = *(const short8*)&Bs[wc * 32 + nt * 16 + m][kk * 32 + g * 8];
#pragma unroll
            for (int mt = 0; mt < 4; mt++)
#pragma unroll
                for (int nt = 0; nt < 2; nt++)
                    acc[mt][nt] = __builtin_amdgcn_mfma_f32_16x16x32_bf16(af[mt], bf2[nt], acc[mt][nt], 0, 0, 0);
        }
    }

    float bv[2];
    bv[0] = bias[n0 + wc * 32 + m];
    bv[1] = bias[n0 + wc * 32 + 16 + m];
#pragma unroll
    for (int mt = 0; mt < 4; mt++)
#pragma unroll
        for (int nt = 0; nt < 2; nt++)
#pragma unroll
            for (int r = 0; r < 4; r++)
                C[(size_t)(m0 + wr * 64 + mt * 16 + g * 4 + r) * DIMC + n0 + wc * 32 + nt * 16 + m] =
                    acc[mt][nt][r] + bv[nt];
}

extern "C" void kernel_launch(void* const* d_in, const int* in_sizes, int n_in,
                              void* d_out, int out_size, void* d_ws, size_t ws_size,
                              hipStream_t stream) {
    const float* x     = (const float*)d_in[0];
    const float* w_qkv = (const float*)d_in[1];
    const float* b_qkv = (const float*)d_in[2];
    const float* w_out = (const float*)d_in[3];
    const float* b_out = (const float*)d_in[4];
    float* out = (float*)d_out;

    const size_t HSZ = (size_t)BATCH * NHEADS * SEQ * HDIM;  // 2M elems
    short* xb  = (short*)d_ws;
    short* wqb = xb + NX;
    short* wob = wqb + NQW;
    short* qw  = wob + NOW;
    short* kw  = qw + HSZ;
    short* vw  = kw + HSZ;
    short* zb  = vw + HSZ;

    cvt_bf16<<<(NX + NQW + NOW) / 1024, 256, 0, stream>>>(x, w_qkv, w_out, xb, wqb, wob);
    qkv_mfma<<<dim3(6, 64), 256, 0, stream>>>(xb, wqb, b_qkv, qw, kw, vw);
    attn_stream<<<dim3(16, 32), 256, 0, stream>>>(qw, kw, vw, zb);
    out_mfma<<<dim3(4, 64), 256, 0, stream>>>(zb, wob, b_out, out);
}